// Round 2
// baseline (759.085 us; speedup 1.0000x reference)
//
#include <hip/hip_runtime.h>
#include <hip/hip_bf16.h>
#include <stdint.h>

#define IMG_H 96
#define IMG_W 96
#define IMG_C 3
#define HO    90                 // 96-7+1
#define NPAT  8100               // 90*90
#define NPAD  8192
#define DDIM  147                // 3*7*7
#define KPAD  160                // padded K (5 chunks of 32)
#define NCHK  5
#define BATCH 4
#define TILE  128
#define ALPHA 0.05f

typedef __attribute__((ext_vector_type(8))) short short8;
typedef __attribute__((ext_vector_type(4))) float f32x4;

__device__ __forceinline__ void async16(const void* g, void* l) {
    __builtin_amdgcn_global_load_lds(
        (const __attribute__((address_space(1))) unsigned int*)g,
        (__attribute__((address_space(3))) unsigned int*)l,
        16, 0, 0);
}

// -------------------- patch extraction + squared norms --------------------
__global__ __launch_bounds__(256) void extract_patches(
    const float* __restrict__ img,          // [B][3][96][96]
    __hip_bfloat16* __restrict__ pat,       // [B][NPAD][KPAD]
    float* __restrict__ nrm)                // [B][NPAD]
{
    int wid  = threadIdx.x >> 6;
    int lane = threadIdx.x & 63;
    int pidx = blockIdx.x * 4 + wid;        // 0..8191
    int b    = blockIdx.y;
    if (pidx >= NPAD) return;
    const float* im = img + (size_t)b * (IMG_C * IMG_H * IMG_W);
    __hip_bfloat16* pp = pat + ((size_t)b * NPAD + pidx) * KPAD;
    int r = pidx / HO, c = pidx - r * HO;
    bool valid = pidx < NPAT;
    float ss = 0.f;
    for (int d = lane; d < KPAD; d += 64) {
        float v = 0.f;
        if (valid && d < DDIM) {
            int ch  = d / 49;
            int rem = d - ch * 49;
            int pr  = rem / 7, pc = rem - pr * 7;
            v = im[ch * (IMG_H * IMG_W) + (r + pr) * IMG_W + (c + pc)];
        }
        pp[d] = __float2bfloat16(v);
        ss += v * v;
    }
    for (int s = 32; s; s >>= 1) ss += __shfl_down(ss, s);
    if (lane == 0) nrm[(size_t)b * NPAD + pidx] = ss;
}

// -------------------- init min arrays to +inf bits --------------------
__global__ void init_mins(unsigned* __restrict__ row_min,
                          unsigned* __restrict__ col_min) {
    int i = blockIdx.x * blockDim.x + threadIdx.x;
    if (i < BATCH * NPAD) {
        row_min[i] = 0x7f800000u;
        col_min[i] = 0x7f800000u;
    }
}

// -------------------- fused GEMM + min epilogues --------------------
// Full-K-in-LDS single-stage: 20 global_load_lds -> ONE barrier -> 80 MFMA.
// LDS tiles swizzled (slot16 ^= (row>>1)&3) via pre-swizzled global source
// (rule #21: linear dest + inverse-swz source + swz read) -> conflict-free.
template <int PASS>
__global__ __launch_bounds__(256, 2) void gemm_pass(
    const __hip_bfloat16* __restrict__ Xp,   // [B][NPAD][KPAD] cols i
    const __hip_bfloat16* __restrict__ Yp,   // [B][NPAD][KPAD] rows j
    const float* __restrict__ x2,
    const float* __restrict__ y2,
    unsigned* __restrict__ row_min,
    unsigned* __restrict__ col_min)
{
    __shared__ __align__(16) __hip_bfloat16 Alds[NCHK][TILE][32]; // 40 KB
    __shared__ __align__(16) __hip_bfloat16 Blds[NCHK][TILE][32]; // 40 KB

    // bijective XCD chunk swizzle: 16384 blocks = 8 XCDs x 2048
    int lin = blockIdx.x;
    int xid = (lin & 7) * 2048 + (lin >> 3);
    int bz  = xid >> 12;                 // image (chunk spans half an image)
    int rem = xid & 4095;
    int tJ  = rem >> 6;                  // row tile (Y)
    int tI  = rem & 63;                  // col tile (X)

    int tid = threadIdx.x;
    int wid = tid >> 6, lane = tid & 63;
    int wr = wid >> 1, wc = wid & 1;

    const __hip_bfloat16* Abase = Yp + ((size_t)bz * NPAD + tJ * TILE) * KPAD;
    const __hip_bfloat16* Bbase = Xp + ((size_t)bz * NPAD + tI * TILE) * KPAD;

    // ---- stage everything: 5 chunks x 2 q-subtiles x {A,B} = 20 async16 ----
    int l4  = lane >> 2;                 // row within 16-row group
    int sst = lane & 3;                  // stored 16B slot (linear in LDS)
    for (int c = 0; c < NCHK; ++c)
        for (int qq = 0; qq < 2; ++qq) {
            int q    = wid * 2 + qq;
            int row  = q * 16 + l4;
            int slog = sst ^ ((row >> 1) & 3);           // inverse swizzle on src
            size_t goff = (size_t)row * KPAD + c * 32 + slog * 8;
            async16(Abase + goff, &Alds[c][q * 16][0]);
            async16(Bbase + goff, &Blds[c][q * 16][0]);
        }
    __syncthreads();   // single vmcnt(0) drain for the whole block

    // ---- compute: conflict-free swizzled ds_read_b128 + MFMA ----
    f32x4 acc[4][4] = {};
    int arow  = wr * 64 + (lane & 15);
    int brow  = wc * 64 + (lane & 15);
    int sread = ((lane >> 4) ^ ((lane >> 1) & 3)) * 8;   // swizzled read slot
    for (int c = 0; c < NCHK; ++c) {
        short8 a[4], b[4];
        for (int m = 0; m < 4; ++m)
            a[m] = *(const short8*)&Alds[c][arow + m * 16][sread];
        for (int n = 0; n < 4; ++n)
            b[n] = *(const short8*)&Blds[c][brow + n * 16][sread];
        for (int m = 0; m < 4; ++m)
            for (int n = 0; n < 4; ++n)
                acc[m][n] = __builtin_amdgcn_mfma_f32_16x16x32_bf16(
                    a[m], b[n], acc[m][n], 0, 0, 0);
    }

    // ---- epilogue ----
    const float invD = 1.0f / (float)DDIM;
    int rbase_l = wr * 64 + (lane >> 4) * 4;  // + m*16 + reg
    int cbase_l = wc * 64 + (lane & 15);      // + n*16
    int growb = tJ * TILE;
    int gcolb = tI * TILE;
    const float* x2b = x2 + (size_t)bz * NPAD + gcolb;
    const float* y2b = y2 + (size_t)bz * NPAD + growb;

    float xv[4];
    for (int n = 0; n < 4; ++n) xv[n] = x2b[cbase_l + n * 16];

    if (PASS == 1) {
        for (int m = 0; m < 4; ++m)
            for (int reg = 0; reg < 4; ++reg) {
                int lr = rbase_l + m * 16 + reg;
                float yv = y2b[lr];
                float rmin = __builtin_inff();
                for (int n = 0; n < 4; ++n) {
                    float dd = (yv + xv[n] - 2.0f * acc[m][n][reg]) * invD;
                    dd = fmaxf(dd, 0.0f);
                    if (gcolb + cbase_l + n * 16 >= NPAT) dd = __builtin_inff();
                    rmin = fminf(rmin, dd);
                }
                for (int s = 1; s < 16; s <<= 1)
                    rmin = fminf(rmin, __shfl_xor(rmin, s));
                int grow = growb + lr;
                if ((lane & 15) == 0 && grow < NPAT)
                    atomicMin(&row_min[(size_t)bz * NPAD + grow],
                              __float_as_uint(rmin));
            }
    } else {
        const unsigned* rmb = row_min + (size_t)bz * NPAD + growb;
        float rcp16[4][4];
        for (int m = 0; m < 4; ++m)
            for (int reg = 0; reg < 4; ++reg) {
                float rm = __uint_as_float(rmb[rbase_l + m * 16 + reg]);
                rcp16[m][reg] = 1.0f / (rm + ALPHA);  // +inf row -> 0, masked below
            }
        for (int n = 0; n < 4; ++n) {
            float cmin = __builtin_inff();
            for (int m = 0; m < 4; ++m)
                for (int reg = 0; reg < 4; ++reg) {
                    int lr = rbase_l + m * 16 + reg;
                    float yv = y2b[lr];
                    float dd = (yv + xv[n] - 2.0f * acc[m][n][reg]) * invD;
                    dd = fmaxf(dd, 0.0f);
                    float v = dd * rcp16[m][reg];
                    if (growb + lr >= NPAT) v = __builtin_inff();
                    cmin = fminf(cmin, v);
                }
            cmin = fminf(cmin, __shfl_xor(cmin, 16));
            cmin = fminf(cmin, __shfl_xor(cmin, 32));
            int gcol = gcolb + cbase_l + n * 16;
            if ((lane >> 4) == 0 && gcol < NPAT)
                atomicMin(&col_min[(size_t)bz * NPAD + gcol],
                          __float_as_uint(cmin));
        }
    }
}

// -------------------- final mean --------------------
__global__ __launch_bounds__(256) void final_reduce(
    const unsigned* __restrict__ col_min, float* __restrict__ out)
{
    __shared__ float sdata[256];
    float s = 0.f;
    for (int idx = threadIdx.x; idx < BATCH * NPAT; idx += 256) {
        int b = idx / NPAT;
        int i = idx - b * NPAT;
        s += __uint_as_float(col_min[(size_t)b * NPAD + i]);
    }
    sdata[threadIdx.x] = s;
    __syncthreads();
    for (int t = 128; t; t >>= 1) {
        if (threadIdx.x < t) sdata[threadIdx.x] += sdata[threadIdx.x + t];
        __syncthreads();
    }
    if (threadIdx.x == 0) out[0] = sdata[0] / (float)(BATCH * NPAT);
}

extern "C" void kernel_launch(void* const* d_in, const int* in_sizes, int n_in,
                              void* d_out, int out_size, void* d_ws, size_t ws_size,
                              hipStream_t stream) {
    const float* x = (const float*)d_in[0];
    const float* y = (const float*)d_in[1];
    float* out = (float*)d_out;

    char* ws = (char*)d_ws;
    size_t patSz = (size_t)BATCH * NPAD * KPAD * sizeof(__hip_bfloat16); // 10.5 MB
    __hip_bfloat16* Xp = (__hip_bfloat16*)ws;
    __hip_bfloat16* Yp = (__hip_bfloat16*)(ws + patSz);
    float* x2 = (float*)(ws + 2 * patSz);
    float* y2 = x2 + BATCH * NPAD;
    unsigned* row_min = (unsigned*)(y2 + BATCH * NPAD);
    unsigned* col_min = row_min + BATCH * NPAD;

    dim3 eg(NPAD / 4, BATCH);
    extract_patches<<<eg, 256, 0, stream>>>(x, Xp, x2);
    extract_patches<<<eg, 256, 0, stream>>>(y, Yp, y2);

    init_mins<<<(BATCH * NPAD + 255) / 256, 256, 0, stream>>>(row_min, col_min);

    int nblk = (NPAD / TILE) * (NPAD / TILE) * BATCH;   // 16384
    gemm_pass<1><<<nblk, 256, 0, stream>>>(Xp, Yp, x2, y2, row_min, col_min);
    gemm_pass<2><<<nblk, 256, 0, stream>>>(Xp, Yp, x2, y2, row_min, col_min);

    final_reduce<<<1, 256, 0, stream>>>(col_min, out);
}

// Round 3
// 541.744 us; speedup vs baseline: 1.4012x; 1.4012x over previous
//
#include <hip/hip_runtime.h>
#include <hip/hip_bf16.h>
#include <stdint.h>

#define IMG_H 96
#define IMG_W 96
#define IMG_C 3
#define HO    90                 // 96-7+1
#define NPAT  8100               // 90*90
#define NPAD  8192
#define DDIM  147                // 3*7*7
#define KPAD  160                // padded K (5 chunks of 32)
#define NCHK  5
#define BATCH 4
#define TILE  128
#define ALPHA 0.05f

typedef __attribute__((ext_vector_type(8))) short short8;
typedef __attribute__((ext_vector_type(4))) float f32x4;

__device__ __forceinline__ void async16(const void* g, void* l) {
    __builtin_amdgcn_global_load_lds(
        (const __attribute__((address_space(1))) unsigned int*)g,
        (__attribute__((address_space(3))) unsigned int*)l,
        16, 0, 0);
}

// -------------------- patch extraction + squared norms --------------------
__global__ __launch_bounds__(256) void extract_patches(
    const float* __restrict__ img,          // [B][3][96][96]
    __hip_bfloat16* __restrict__ pat,       // [B][NPAD][KPAD]
    float* __restrict__ nrm)                // [B][NPAD]
{
    int wid  = threadIdx.x >> 6;
    int lane = threadIdx.x & 63;
    int pidx = blockIdx.x * 4 + wid;        // 0..8191
    int b    = blockIdx.y;
    if (pidx >= NPAD) return;
    const float* im = img + (size_t)b * (IMG_C * IMG_H * IMG_W);
    __hip_bfloat16* pp = pat + ((size_t)b * NPAD + pidx) * KPAD;
    int r = pidx / HO, c = pidx - r * HO;
    bool valid = pidx < NPAT;
    float ss = 0.f;
    for (int d = lane; d < KPAD; d += 64) {
        float v = 0.f;
        if (valid && d < DDIM) {
            int ch  = d / 49;
            int rem = d - ch * 49;
            int pr  = rem / 7, pc = rem - pr * 7;
            v = im[ch * (IMG_H * IMG_W) + (r + pr) * IMG_W + (c + pc)];
        }
        pp[d] = __float2bfloat16(v);
        ss += v * v;
    }
    for (int s = 32; s; s >>= 1) ss += __shfl_down(ss, s);
    if (lane == 0) nrm[(size_t)b * NPAD + pidx] = ss;
}

// -------------------- init min arrays to +inf bits --------------------
__global__ void init_mins(unsigned* __restrict__ row_min,
                          unsigned* __restrict__ col_min) {
    int i = blockIdx.x * blockDim.x + threadIdx.x;
    if (i < BATCH * NPAD) {
        row_min[i] = 0x7f800000u;
        col_min[i] = 0x7f800000u;
    }
}

// -------------------- fused GEMM + min epilogues --------------------
// 2-phase double-buffered K-chunks (T3-minimum), swizzled LDS (0 conflicts),
// XCD-aware block swizzle. One barrier per chunk; prefetch overlaps MFMA.
template <int PASS>
__global__ __launch_bounds__(256, 4) void gemm_pass(
    const __hip_bfloat16* __restrict__ Xp,   // [B][NPAD][KPAD] cols i
    const __hip_bfloat16* __restrict__ Yp,   // [B][NPAD][KPAD] rows j
    const float* __restrict__ x2,
    const float* __restrict__ y2,
    unsigned* __restrict__ row_min,
    unsigned* __restrict__ col_min)
{
    __shared__ __align__(16) __hip_bfloat16 Abuf[2][TILE][32]; // 2 x 8 KB
    __shared__ __align__(16) __hip_bfloat16 Bbuf[2][TILE][32]; // 2 x 8 KB
    __shared__ float y2s[TILE], x2s[TILE], rms[TILE];

    // bijective XCD chunk swizzle: 16384 blocks = 8 XCDs x 2048
    int lin = blockIdx.x;
    int xid = (lin & 7) * 2048 + (lin >> 3);
    int bz  = xid >> 12;                 // image
    int rem = xid & 4095;
    int tJ  = rem >> 6;                  // row tile (Y), slow -> A panel reused
    int tI  = rem & 63;                  // col tile (X), fast

    int tid = threadIdx.x;
    int wid = tid >> 6, lane = tid & 63;
    int wr = wid >> 1, wc = wid & 1;

    const __hip_bfloat16* Abase = Yp + ((size_t)bz * NPAD + tJ * TILE) * KPAD;
    const __hip_bfloat16* Bbase = Xp + ((size_t)bz * NPAD + tI * TILE) * KPAD;

    // epilogue scalars -> LDS (broadcast reads later)
    if (tid < TILE) {
        y2s[tid] = y2[(size_t)bz * NPAD + tJ * TILE + tid];
        if (PASS == 2) {
            float rm = __uint_as_float(row_min[(size_t)bz * NPAD + tJ * TILE + tid]);
            rms[tid] = 1.0f / (rm + ALPHA);  // +inf pad row -> 0, masked below
        }
    } else {
        x2s[tid - TILE] = x2[(size_t)bz * NPAD + tI * TILE + tid - TILE];
    }

    int l4  = lane >> 2;                 // row within 16-row subtile
    int sst = lane & 3;                  // linear stored 16B slot

    // stage chunk c (32 cols) of A and B into buffer `buf`
    auto stage = [&](int buf, int c) {
        for (int qq = 0; qq < 2; ++qq) {
            int q    = wid * 2 + qq;
            int row  = q * 16 + l4;
            int slog = sst ^ ((row >> 1) & 3);            // inverse swz on src
            size_t goff = (size_t)row * KPAD + c * 32 + slog * 8;
            async16(Abase + goff, &Abuf[buf][q * 16][0]);
            async16(Bbase + goff, &Bbuf[buf][q * 16][0]);
        }
    };

    stage(0, 0);
    __syncthreads();                     // drain prologue loads

    f32x4 acc[4][4] = {};
    int arow  = wr * 64 + (lane & 15);
    int brow  = wc * 64 + (lane & 15);
    int sread = ((lane >> 4) ^ ((lane >> 1) & 3)) * 8;    // swizzled read slot

    for (int c = 0; c < NCHK; ++c) {
        int cur = c & 1;
        if (c + 1 < NCHK) stage(cur ^ 1, c + 1);          // prefetch next chunk
        short8 a[4], b[4];
        for (int m = 0; m < 4; ++m)
            a[m] = *(const short8*)&Abuf[cur][arow + m * 16][sread];
        for (int n = 0; n < 4; ++n)
            b[n] = *(const short8*)&Bbuf[cur][brow + n * 16][sread];
        for (int m = 0; m < 4; ++m)
            for (int n = 0; n < 4; ++n)
                acc[m][n] = __builtin_amdgcn_mfma_f32_16x16x32_bf16(
                    a[m], b[n], acc[m][n], 0, 0, 0);
        __syncthreads();                 // drains prefetch vmcnt + sync bufs
    }

    // ---- epilogue ----
    const float invD = 1.0f / (float)DDIM;
    int rbase_l = wr * 64 + (lane >> 4) * 4;  // + m*16 + reg
    int cbase_l = wc * 64 + (lane & 15);      // + n*16
    int growb = tJ * TILE;
    int gcolb = tI * TILE;

    float xv[4];
    for (int n = 0; n < 4; ++n) xv[n] = x2s[cbase_l + n * 16];

    if (PASS == 1) {
        for (int m = 0; m < 4; ++m)
            for (int reg = 0; reg < 4; ++reg) {
                int lr = rbase_l + m * 16 + reg;
                float yv = y2s[lr];
                float rmin = __builtin_inff();
                for (int n = 0; n < 4; ++n) {
                    float dd = (yv + xv[n] - 2.0f * acc[m][n][reg]) * invD;
                    dd = fmaxf(dd, 0.0f);
                    if (gcolb + cbase_l + n * 16 >= NPAT) dd = __builtin_inff();
                    rmin = fminf(rmin, dd);
                }
                for (int s = 1; s < 16; s <<= 1)
                    rmin = fminf(rmin, __shfl_xor(rmin, s));
                int grow = growb + lr;
                if ((lane & 15) == 0 && grow < NPAT)
                    atomicMin(&row_min[(size_t)bz * NPAD + grow],
                              __float_as_uint(rmin));
            }
    } else {
        for (int n = 0; n < 4; ++n) {
            float cmin = __builtin_inff();
            for (int m = 0; m < 4; ++m)
                for (int reg = 0; reg < 4; ++reg) {
                    int lr = rbase_l + m * 16 + reg;
                    float dd = (y2s[lr] + xv[n] - 2.0f * acc[m][n][reg]) * invD;
                    dd = fmaxf(dd, 0.0f);
                    float v = dd * rms[lr];
                    if (growb + lr >= NPAT) v = __builtin_inff();
                    cmin = fminf(cmin, v);
                }
            cmin = fminf(cmin, __shfl_xor(cmin, 16));
            cmin = fminf(cmin, __shfl_xor(cmin, 32));
            int gcol = gcolb + cbase_l + n * 16;
            if ((lane >> 4) == 0 && gcol < NPAT)
                atomicMin(&col_min[(size_t)bz * NPAD + gcol],
                          __float_as_uint(cmin));
        }
    }
}

// -------------------- final mean --------------------
__global__ __launch_bounds__(256) void final_reduce(
    const unsigned* __restrict__ col_min, float* __restrict__ out)
{
    __shared__ float sdata[256];
    float s = 0.f;
    for (int idx = threadIdx.x; idx < BATCH * NPAT; idx += 256) {
        int b = idx / NPAT;
        int i = idx - b * NPAT;
        s += __uint_as_float(col_min[(size_t)b * NPAD + i]);
    }
    sdata[threadIdx.x] = s;
    __syncthreads();
    for (int t = 128; t; t >>= 1) {
        if (threadIdx.x < t) sdata[threadIdx.x] += sdata[threadIdx.x + t];
        __syncthreads();
    }
    if (threadIdx.x == 0) out[0] = sdata[0] / (float)(BATCH * NPAT);
}

extern "C" void kernel_launch(void* const* d_in, const int* in_sizes, int n_in,
                              void* d_out, int out_size, void* d_ws, size_t ws_size,
                              hipStream_t stream) {
    const float* x = (const float*)d_in[0];
    const float* y = (const float*)d_in[1];
    float* out = (float*)d_out;

    char* ws = (char*)d_ws;
    size_t patSz = (size_t)BATCH * NPAD * KPAD * sizeof(__hip_bfloat16); // 10.5 MB
    __hip_bfloat16* Xp = (__hip_bfloat16*)ws;
    __hip_bfloat16* Yp = (__hip_bfloat16*)(ws + patSz);
    float* x2 = (float*)(ws + 2 * patSz);
    float* y2 = x2 + BATCH * NPAD;
    unsigned* row_min = (unsigned*)(y2 + BATCH * NPAD);
    unsigned* col_min = row_min + BATCH * NPAD;

    dim3 eg(NPAD / 4, BATCH);
    extract_patches<<<eg, 256, 0, stream>>>(x, Xp, x2);
    extract_patches<<<eg, 256, 0, stream>>>(y, Yp, y2);

    init_mins<<<(BATCH * NPAD + 255) / 256, 256, 0, stream>>>(row_min, col_min);

    int nblk = (NPAD / TILE) * (NPAD / TILE) * BATCH;   // 16384
    gemm_pass<1><<<nblk, 256, 0, stream>>>(Xp, Yp, x2, y2, row_min, col_min);
    gemm_pass<2><<<nblk, 256, 0, stream>>>(Xp, Yp, x2, y2, row_min, col_min);

    final_reduce<<<1, 256, 0, stream>>>(col_min, out);
}

// Round 4
// 336.042 us; speedup vs baseline: 2.2589x; 1.6121x over previous
//
#include <hip/hip_runtime.h>
#include <hip/hip_bf16.h>
#include <stdint.h>

#define IMG_H 96
#define IMG_W 96
#define IMG_C 3
#define HO    90                 // 96-7+1
#define NPAT  8100               // 90*90
#define NPAD  8192
#define DDIM  147                // 3*7*7
#define KPAD  160                // padded K (5 chunks of 32)
#define NCHK  5
#define BATCH 4
#define TILE  128
#define ALPHA 0.05f

typedef __attribute__((ext_vector_type(8))) short short8;
typedef __attribute__((ext_vector_type(4))) float f32x4;

__device__ __forceinline__ void async16(const void* g, void* l) {
    __builtin_amdgcn_global_load_lds(
        (const __attribute__((address_space(1))) unsigned int*)g,
        (__attribute__((address_space(3))) unsigned int*)l,
        16, 0, 0);
}

// ---------- patch extraction + squared norms (+ min-init, + out zero) ----------
__global__ __launch_bounds__(256) void extract_patches(
    const float* __restrict__ img,          // [B][3][96][96]
    __hip_bfloat16* __restrict__ pat,       // [B][NPAD][KPAD]
    float* __restrict__ nrm,                // [B][NPAD]
    unsigned* __restrict__ mininit,         // row_min or col_min -> +inf
    float* __restrict__ outzero)            // may be null
{
    int wid  = threadIdx.x >> 6;
    int lane = threadIdx.x & 63;
    int pidx = blockIdx.x * 4 + wid;        // 0..8191
    int b    = blockIdx.y;
    if (pidx >= NPAD) return;
    if (outzero && blockIdx.x == 0 && blockIdx.y == 0 && threadIdx.x == 0)
        outzero[0] = 0.f;
    const float* im = img + (size_t)b * (IMG_C * IMG_H * IMG_W);
    __hip_bfloat16* pp = pat + ((size_t)b * NPAD + pidx) * KPAD;
    int r = pidx / HO, c = pidx - r * HO;
    bool valid = pidx < NPAT;
    float ss = 0.f;
    for (int d = lane; d < KPAD; d += 64) {
        float v = 0.f;
        if (valid && d < DDIM) {
            int ch  = d / 49;
            int rem = d - ch * 49;
            int pr  = rem / 7, pc = rem - pr * 7;
            v = im[ch * (IMG_H * IMG_W) + (r + pr) * IMG_W + (c + pc)];
        }
        pp[d] = __float2bfloat16(v);
        ss += v * v;
    }
    for (int s = 32; s; s >>= 1) ss += __shfl_down(ss, s);
    if (lane == 0) {
        nrm[(size_t)b * NPAD + pidx] = ss;
        mininit[(size_t)b * NPAD + pidx] = 0x7f800000u;  // +inf bits
    }
}

// -------------------- fused GEMM + min epilogues --------------------
// R1 structure (2 barriers/chunk, single static LDS buffer) + LDS XOR-swizzle
// (rule #21: linear LDS dest, inverse-swz global source, swz read offsets).
template <int PASS>
__global__ __launch_bounds__(256, 2) void gemm_pass(
    const __hip_bfloat16* __restrict__ Xp,   // [B][NPAD][KPAD] cols i
    const __hip_bfloat16* __restrict__ Yp,   // [B][NPAD][KPAD] rows j
    const float* __restrict__ x2,
    const float* __restrict__ y2,
    unsigned* __restrict__ row_min,
    unsigned* __restrict__ col_min)
{
    __shared__ __align__(16) __hip_bfloat16 Alds[TILE * 32];  // rows (Yp)
    __shared__ __align__(16) __hip_bfloat16 Blds[TILE * 32];  // cols (Xp)
    __shared__ float y2s[TILE], x2s[TILE], rms[TILE];

    int bz  = blockIdx.z;
    int tI  = blockIdx.x;   // col tile
    int tJ  = blockIdx.y;   // row tile
    int tid = threadIdx.x;
    int wid = tid >> 6, lane = tid & 63;
    int wr = wid >> 1, wc = wid & 1;

    const __hip_bfloat16* Abase = Yp + ((size_t)bz * NPAD + tJ * TILE) * KPAD;
    const __hip_bfloat16* Bbase = Xp + ((size_t)bz * NPAD + tI * TILE) * KPAD;

    if (tid < TILE) {
        y2s[tid] = y2[(size_t)bz * NPAD + tJ * TILE + tid];
        if (PASS == 2) {
            float rm = __uint_as_float(row_min[(size_t)bz * NPAD + tJ * TILE + tid]);
            rms[tid] = 1.0f / (rm + ALPHA);  // +inf pad row -> 0, masked later
        }
    } else {
        int t = tid - TILE;
        x2s[t] = x2[(size_t)bz * NPAD + tI * TILE + t];
    }

    f32x4 acc[4][4] = {};
    int srow = (lane >> 2);          // row within 16-row subtile
    int sst  = (lane & 3);           // linear stored 16B slot

    for (int k0 = 0; k0 < KPAD; k0 += 32) {
        // stage A/B 128x32 bf16 tiles; wave wid stages subtiles {2wid, 2wid+1}
        for (int qq = 0; qq < 2; ++qq) {
            int q    = wid * 2 + qq;
            int row  = q * 16 + srow;
            int slog = sst ^ ((row >> 1) & 3);           // inverse swz on src
            size_t goff = (size_t)row * KPAD + k0 + slog * 8;
            async16(Abase + goff, &Alds[q * 512]);
            async16(Bbase + goff, &Blds[q * 512]);
        }
        __syncthreads();

        short8 a[4], bq[4];
        int arow  = wr * 64 + (lane & 15);
        int brow  = wc * 64 + (lane & 15);
        int sread = ((lane >> 4) ^ ((lane >> 1) & 3)) * 8;  // swz read slot
        for (int m = 0; m < 4; ++m)
            a[m] = *(const short8*)&Alds[(arow + m * 16) * 32 + sread];
        for (int n = 0; n < 4; ++n)
            bq[n] = *(const short8*)&Blds[(brow + n * 16) * 32 + sread];
        for (int m = 0; m < 4; ++m)
            for (int n = 0; n < 4; ++n)
                acc[m][n] = __builtin_amdgcn_mfma_f32_16x16x32_bf16(
                    a[m], bq[n], acc[m][n], 0, 0, 0);
        __syncthreads();
    }

    // ---- epilogue ----
    const float invD = 1.0f / (float)DDIM;
    int rbase_l = wr * 64 + (lane >> 4) * 4;  // + m*16 + reg
    int cbase_l = wc * 64 + (lane & 15);      // + n*16
    int growb = tJ * TILE;
    int gcolb = tI * TILE;

    float xv[4];
    for (int n = 0; n < 4; ++n) xv[n] = x2s[cbase_l + n * 16];

    if (PASS == 1) {
        for (int m = 0; m < 4; ++m)
            for (int reg = 0; reg < 4; ++reg) {
                int lr = rbase_l + m * 16 + reg;
                float yv = y2s[lr];
                float rmin = __builtin_inff();
                for (int n = 0; n < 4; ++n) {
                    float dd = (yv + xv[n] - 2.0f * acc[m][n][reg]) * invD;
                    dd = fmaxf(dd, 0.0f);
                    if (gcolb + cbase_l + n * 16 >= NPAT) dd = __builtin_inff();
                    rmin = fminf(rmin, dd);
                }
                for (int s = 1; s < 16; s <<= 1)
                    rmin = fminf(rmin, __shfl_xor(rmin, s));
                int grow = growb + lr;
                if ((lane & 15) == 0 && grow < NPAT)
                    atomicMin(&row_min[(size_t)bz * NPAD + grow],
                              __float_as_uint(rmin));
            }
    } else {
        for (int n = 0; n < 4; ++n) {
            float cmin = __builtin_inff();
            for (int m = 0; m < 4; ++m)
                for (int reg = 0; reg < 4; ++reg) {
                    int lr = rbase_l + m * 16 + reg;
                    float dd = (y2s[lr] + xv[n] - 2.0f * acc[m][n][reg]) * invD;
                    dd = fmaxf(dd, 0.0f);
                    float v = dd * rms[lr];
                    if (growb + lr >= NPAT) v = __builtin_inff();
                    cmin = fminf(cmin, v);
                }
            cmin = fminf(cmin, __shfl_xor(cmin, 16));
            cmin = fminf(cmin, __shfl_xor(cmin, 32));
            int gcol = gcolb + cbase_l + n * 16;
            if ((lane >> 4) == 0 && gcol < NPAT)
                atomicMin(&col_min[(size_t)bz * NPAD + gcol],
                          __float_as_uint(cmin));
        }
    }
}

// -------------------- final mean (parallel, scaled atomicAdd) --------------------
__global__ __launch_bounds__(256) void final_reduce(
    const unsigned* __restrict__ col_min, float* __restrict__ out)
{
    __shared__ float sdata[256];
    float s = 0.f;
    for (int idx = blockIdx.x * 256 + threadIdx.x; idx < BATCH * NPAT;
         idx += gridDim.x * 256) {
        int b = idx / NPAT;
        int i = idx - b * NPAT;
        s += __uint_as_float(col_min[(size_t)b * NPAD + i]);
    }
    sdata[threadIdx.x] = s;
    __syncthreads();
    for (int t = 128; t; t >>= 1) {
        if (threadIdx.x < t) sdata[threadIdx.x] += sdata[threadIdx.x + t];
        __syncthreads();
    }
    if (threadIdx.x == 0)
        atomicAdd(out, sdata[0] * (1.0f / (float)(BATCH * NPAT)));
}

extern "C" void kernel_launch(void* const* d_in, const int* in_sizes, int n_in,
                              void* d_out, int out_size, void* d_ws, size_t ws_size,
                              hipStream_t stream) {
    const float* x = (const float*)d_in[0];
    const float* y = (const float*)d_in[1];
    float* out = (float*)d_out;

    char* ws = (char*)d_ws;
    size_t patSz = (size_t)BATCH * NPAD * KPAD * sizeof(__hip_bfloat16); // 10.5 MB
    __hip_bfloat16* Xp = (__hip_bfloat16*)ws;
    __hip_bfloat16* Yp = (__hip_bfloat16*)(ws + patSz);
    float* x2 = (float*)(ws + 2 * patSz);
    float* y2 = x2 + BATCH * NPAD;
    unsigned* row_min = (unsigned*)(y2 + BATCH * NPAD);
    unsigned* col_min = row_min + BATCH * NPAD;

    dim3 eg(NPAD / 4, BATCH);
    // x-extract inits col_min and zeroes out; y-extract inits row_min
    extract_patches<<<eg, 256, 0, stream>>>(x, Xp, x2, col_min, out);
    extract_patches<<<eg, 256, 0, stream>>>(y, Yp, y2, row_min, nullptr);

    dim3 gg(NPAD / TILE, NPAD / TILE, BATCH);   // (64, 64, 4) as in R1
    gemm_pass<1><<<gg, 256, 0, stream>>>(Xp, Yp, x2, y2, row_min, col_min);
    gemm_pass<2><<<gg, 256, 0, stream>>>(Xp, Yp, x2, y2, row_min, col_min);

    final_reduce<<<64, 256, 0, stream>>>(col_min, out);
}